// Round 3
// baseline (130.414 us; speedup 1.0000x reference)
//
#include <hip/hip_runtime.h>
#include <math.h>

// tanh(delta^T M delta) for pairs of 20 amino-acid feature rows.
// idx in [0,20) => only 400 distinct outputs. Each block computes the
// 400-entry table (218 KFLOP, hidden under the memory-bound gather), then
// does a vectorized int4/float4 gather.
// Traffic floor: 67 MB idx read + 33.5 MB out write ~= 16 us @ 6.3 TB/s.

constexpr int NUM_AA = 20;
constexpr int FEAT   = 16;
constexpr int TABLE  = NUM_AA * NUM_AA; // 400

__global__ __launch_bounds__(256) void snack_fused(
    const float* __restrict__ F,        // [20,16]
    const float* __restrict__ M,        // [16,16]
    const int4* __restrict__ ii4,       // idx_i as int4
    const int4* __restrict__ jj4,       // idx_j as int4
    float4* __restrict__ out4,          // output as float4
    int nvec,                           // P/4
    const int* __restrict__ ii_s,       // scalar views for tail
    const int* __restrict__ jj_s,
    float* __restrict__ out_s,
    int tail_start, int total)          // tail handling (P % 4)
{
    __shared__ float s[TABLE];          // 1.6 KB lookup table
    __shared__ float sF[NUM_AA * FEAT]; // 320 floats
    __shared__ float sM[FEAT * FEAT];   // 256 floats

    const int t      = (int)threadIdx.x;
    const int stride = (int)gridDim.x * 256;
    int v = (int)blockIdx.x * 256 + t;

    // Prefetch first index vector BEFORE the table-compute phase so the
    // global-load pipe is busy while the VALU computes the table.
    int4 ii, jj;
    const bool have0 = (v < nvec);
    if (have0) { ii = ii4[v]; jj = jj4[v]; }

    // Stage F, M into LDS.
    for (int k = t; k < NUM_AA * FEAT; k += 256) sF[k] = F[k];
    for (int k = t; k < FEAT * FEAT; k += 256)   sM[k] = M[k];
    __syncthreads();

    // Each thread computes up to 2 of the 400 table entries.
    for (int e = t; e < TABLE; e += 256) {
        const int i = e / NUM_AA;
        const int j = e - i * NUM_AA;
        float delta[FEAT];
#pragma unroll
        for (int d = 0; d < FEAT; ++d)
            delta[d] = sF[i * FEAT + d] - sF[j * FEAT + d];
        float dist = 0.f;
#pragma unroll
        for (int d = 0; d < FEAT; ++d) {
            float md = 0.f;
#pragma unroll
            for (int e2 = 0; e2 < FEAT; ++e2)
                md = fmaf(sM[d * FEAT + e2], delta[e2], md);
            dist = fmaf(delta[d], md, dist);
        }
        s[e] = tanhf(dist);
    }
    __syncthreads();

    // Grid-stride gather: lookup in LDS, float4 store.
    while (v < nvec) {
        float4 o;
        o.x = s[ii.x * NUM_AA + jj.x];
        o.y = s[ii.y * NUM_AA + jj.y];
        o.z = s[ii.z * NUM_AA + jj.z];
        o.w = s[ii.w * NUM_AA + jj.w];
        out4[v] = o;
        v += stride;
        if (v < nvec) { ii = ii4[v]; jj = jj4[v]; }
    }

    // tail (P % 4 != 0) — block 0 handles up to 3 scalars
    if (blockIdx.x == 0) {
        const int p = tail_start + t;
        if (p < total)
            out_s[p] = s[ii_s[p] * NUM_AA + jj_s[p]];
    }
}

extern "C" void kernel_launch(void* const* d_in, const int* in_sizes, int n_in,
                              void* d_out, int out_size, void* d_ws, size_t ws_size,
                              hipStream_t stream)
{
    const float* F   = (const float*)d_in[0];
    const float* M   = (const float*)d_in[1];
    const int*   ii  = (const int*)d_in[2];
    const int*   jj  = (const int*)d_in[3];
    float*       out = (float*)d_out;
    (void)d_ws; (void)ws_size;

    const int P    = in_sizes[2];
    const int nvec = P >> 2;           // 2,097,152 for P = 8,388,608
    const int tail = nvec << 2;        // first scalar index of tail (== P here)

    // 2048 blocks x 256 thr: 8 blocks/CU resident; per-CU table VALU ~2.8 us,
    // hidden under the ~20 us memory-bound gather. (8192 one-shot blocks would
    // cost 4x the redundant table FLOPs — no longer hidden.)
    int blocks = (nvec + 255) / 256;
    if (blocks > 2048) blocks = 2048;
    if (blocks < 1) blocks = 1;

    snack_fused<<<blocks, 256, 0, stream>>>(
        F, M, (const int4*)ii, (const int4*)jj, (float4*)out,
        nvec, ii, jj, out, tail, P);
}

// Round 4
// 109.188 us; speedup vs baseline: 1.1944x; 1.1944x over previous
//
#include <hip/hip_runtime.h>
#include <math.h>

// tanh(delta^T M delta) for pairs of 20 amino-acid feature rows.
// idx in [0,20) => only 400 distinct outputs. Kernel A builds the table
// (1 block, trivial); kernel B is a lean one-shot gather: 2 independent
// int4-pairs per thread (4 loads in flight), LDS table lookup, float4 stores.
// R3 lesson: fusing table-build inflated VGPR to 148 -> latency-bound 50us.
// HBM floor ~ 33 MB write + idx reads largely L3-hit => ~10-14 us kernel.

constexpr int NUM_AA = 20;
constexpr int FEAT   = 16;
constexpr int TABLE  = NUM_AA * NUM_AA; // 400

// ---------------- Kernel A: build the 400-entry lookup table + tail ---------
__global__ __launch_bounds__(512) void build_table(
    const float* __restrict__ F,   // [20,16]
    const float* __restrict__ M,   // [16,16]
    float* __restrict__ tab,       // [400] out (in d_ws)
    const int* __restrict__ ii_s,  // tail handling (P % 8)
    const int* __restrict__ jj_s,
    float* __restrict__ out_s,
    int tail_start, int total)
{
    __shared__ float sF[NUM_AA * FEAT]; // 320 floats
    __shared__ float sM[FEAT * FEAT];   // 256 floats
    __shared__ float sT[TABLE];
    const int t = threadIdx.x;
    for (int k = t; k < NUM_AA * FEAT; k += 512) sF[k] = F[k];
    for (int k = t; k < FEAT * FEAT; k += 512)   sM[k] = M[k];
    __syncthreads();

    if (t < TABLE) {
        const int i = t / NUM_AA;
        const int j = t - i * NUM_AA;
        float delta[FEAT];
#pragma unroll
        for (int d = 0; d < FEAT; ++d)
            delta[d] = sF[i * FEAT + d] - sF[j * FEAT + d];
        float dist = 0.f;
#pragma unroll
        for (int d = 0; d < FEAT; ++d) {
            float md = 0.f;
#pragma unroll
            for (int e = 0; e < FEAT; ++e)
                md = fmaf(sM[d * FEAT + e], delta[e], md);
            dist = fmaf(delta[d], md, dist);
        }
        const float v = tanhf(dist);
        tab[t] = v;
        sT[t]  = v;
    }
    __syncthreads();

    // tail (P % 8 != 0): up to 7 scalar pairs, done here off the hot kernel
    const int p = tail_start + t;
    if (p < total)
        out_s[p] = sT[ii_s[p] * NUM_AA + jj_s[p]];
}

// ---------------- Kernel B: lean one-shot gather, 2 vec4 per thread ---------
__global__ __launch_bounds__(256) void gather_pairs(
    const float* __restrict__ tab,      // [400] in d_ws
    const int4* __restrict__ ii4,       // idx_i as int4
    const int4* __restrict__ jj4,       // idx_j as int4
    float4* __restrict__ out4,          // output as float4
    int nvec)                           // P/4
{
    __shared__ float s[TABLE]; // 1.6 KB

    const int t  = (int)threadIdx.x;
    const int v0 = (int)blockIdx.x * 512 + t;   // first vec4
    const int v1 = v0 + 256;                    // second vec4 (independent)

    // Issue the 4 independent global idx loads FIRST — they complete while
    // the table is staged into LDS and the barrier drains.
    int4 iiA, jjA, iiB, jjB;
    const bool hA = (v0 < nvec);
    const bool hB = (v1 < nvec);
    if (hA) { iiA = ii4[v0]; jjA = jj4[v0]; }
    if (hB) { iiB = ii4[v1]; jjB = jj4[v1]; }

    // Stage table (400 floats, 2 per thread) into LDS.
    if (t < 200) {
        s[t]       = tab[t];
        s[t + 200] = tab[t + 200];
    }
    __syncthreads();

    if (hA) {
        float4 o;
        o.x = s[iiA.x * NUM_AA + jjA.x];
        o.y = s[iiA.y * NUM_AA + jjA.y];
        o.z = s[iiA.z * NUM_AA + jjA.z];
        o.w = s[iiA.w * NUM_AA + jjA.w];
        out4[v0] = o;
    }
    if (hB) {
        float4 o;
        o.x = s[iiB.x * NUM_AA + jjB.x];
        o.y = s[iiB.y * NUM_AA + jjB.y];
        o.z = s[iiB.z * NUM_AA + jjB.z];
        o.w = s[iiB.w * NUM_AA + jjB.w];
        out4[v1] = o;
    }
}

extern "C" void kernel_launch(void* const* d_in, const int* in_sizes, int n_in,
                              void* d_out, int out_size, void* d_ws, size_t ws_size,
                              hipStream_t stream)
{
    const float* F   = (const float*)d_in[0];
    const float* M   = (const float*)d_in[1];
    const int*   ii  = (const int*)d_in[2];
    const int*   jj  = (const int*)d_in[3];
    float*       out = (float*)d_out;
    float*       tab = (float*)d_ws;   // 400 floats = 1.6 KB scratch

    const int P    = in_sizes[2];
    const int nvec = P >> 2;           // 2,097,152 for P = 8,388,608
    const int tail = nvec << 2;        // first scalar index of tail

    build_table<<<1, 512, 0, stream>>>(F, M, tab, ii, jj, out, tail, P);

    // 4096 blocks x 256 thr x 2 vec4 = 2,097,152 vec4s (exact for this P).
    const int blocks = (nvec + 511) / 512;
    gather_pairs<<<blocks, 256, 0, stream>>>(
        tab, (const int4*)ii, (const int4*)jj, (float4*)out, nvec);
}

// Round 5
// 109.020 us; speedup vs baseline: 1.1962x; 1.0015x over previous
//
#include <hip/hip_runtime.h>
#include <math.h>

// tanh(delta^T M delta) for pairs of 20 amino-acid feature rows.
// idx in [0,20) => only 400 distinct outputs. Kernel A builds the table
// (1 block); kernel B gathers: 4 independent int4-pairs per thread
// (8 x 16B loads in flight before the LDS staging barrier), LDS lookup,
// 4 float4 stores. 2048 one-shot blocks x 256 thr x 4 vec4 = exact P/4.
// R3 lesson: fusing table-build -> 148 VGPR, latency-bound 50us. Keep split.
// Floor: ~33.5 MB HBM write + 67 MB idx (mostly L3-hit) => ~10-13 us gather.

constexpr int NUM_AA = 20;
constexpr int FEAT   = 16;
constexpr int TABLE  = NUM_AA * NUM_AA; // 400

// ---------------- Kernel A: build the 400-entry lookup table + tail ---------
__global__ __launch_bounds__(512) void build_table(
    const float* __restrict__ F,   // [20,16]
    const float* __restrict__ M,   // [16,16]
    float* __restrict__ tab,       // [400] out (in d_ws)
    const int* __restrict__ ii_s,  // tail handling (P % 16)
    const int* __restrict__ jj_s,
    float* __restrict__ out_s,
    int tail_start, int total)
{
    __shared__ float sF[NUM_AA * FEAT]; // 320 floats
    __shared__ float sM[FEAT * FEAT];   // 256 floats
    __shared__ float sT[TABLE];
    const int t = threadIdx.x;
    for (int k = t; k < NUM_AA * FEAT; k += 512) sF[k] = F[k];
    for (int k = t; k < FEAT * FEAT; k += 512)   sM[k] = M[k];
    __syncthreads();

    if (t < TABLE) {
        const int i = t / NUM_AA;
        const int j = t - i * NUM_AA;
        float delta[FEAT];
#pragma unroll
        for (int d = 0; d < FEAT; ++d)
            delta[d] = sF[i * FEAT + d] - sF[j * FEAT + d];
        float dist = 0.f;
#pragma unroll
        for (int d = 0; d < FEAT; ++d) {
            float md = 0.f;
#pragma unroll
            for (int e = 0; e < FEAT; ++e)
                md = fmaf(sM[d * FEAT + e], delta[e], md);
            dist = fmaf(delta[d], md, dist);
        }
        const float v = tanhf(dist);
        tab[t] = v;
        sT[t]  = v;
    }
    __syncthreads();

    // tail (P % 16 != 0): up to 15 scalar pairs, done off the hot kernel
    const int p = tail_start + t;
    if (p < total)
        out_s[p] = sT[ii_s[p] * NUM_AA + jj_s[p]];
}

// ---------------- Kernel B: lean one-shot gather, 4 vec4 per thread ---------
__global__ __launch_bounds__(256) void gather_pairs(
    const float* __restrict__ tab,      // [400] in d_ws
    const int4* __restrict__ ii4,       // idx_i as int4
    const int4* __restrict__ jj4,       // idx_j as int4
    float4* __restrict__ out4,          // output as float4
    int nvec)                           // P/4
{
    __shared__ float s[TABLE]; // 1.6 KB

    const int t  = (int)threadIdx.x;
    const int v0 = (int)blockIdx.x * 1024 + t;  // 4 vec4s: v0, +256, +512, +768
    const int v1 = v0 + 256;
    const int v2 = v0 + 512;
    const int v3 = v0 + 768;

    // Issue all 8 independent idx loads FIRST — 128 B in flight per thread
    // while the table is staged into LDS and the barrier drains.
    int4 iiA, jjA, iiB, jjB, iiC, jjC, iiD, jjD;
    const bool hA = (v0 < nvec);
    const bool hB = (v1 < nvec);
    const bool hC = (v2 < nvec);
    const bool hD = (v3 < nvec);
    if (hA) { iiA = ii4[v0]; jjA = jj4[v0]; }
    if (hB) { iiB = ii4[v1]; jjB = jj4[v1]; }
    if (hC) { iiC = ii4[v2]; jjC = jj4[v2]; }
    if (hD) { iiD = ii4[v3]; jjD = jj4[v3]; }

    // Stage table (400 floats, 2 per thread) into LDS.
    if (t < 200) {
        s[t]       = tab[t];
        s[t + 200] = tab[t + 200];
    }
    __syncthreads();

    if (hA) {
        float4 o;
        o.x = s[iiA.x * NUM_AA + jjA.x];
        o.y = s[iiA.y * NUM_AA + jjA.y];
        o.z = s[iiA.z * NUM_AA + jjA.z];
        o.w = s[iiA.w * NUM_AA + jjA.w];
        out4[v0] = o;
    }
    if (hB) {
        float4 o;
        o.x = s[iiB.x * NUM_AA + jjB.x];
        o.y = s[iiB.y * NUM_AA + jjB.y];
        o.z = s[iiB.z * NUM_AA + jjB.z];
        o.w = s[iiB.w * NUM_AA + jjB.w];
        out4[v1] = o;
    }
    if (hC) {
        float4 o;
        o.x = s[iiC.x * NUM_AA + jjC.x];
        o.y = s[iiC.y * NUM_AA + jjC.y];
        o.z = s[iiC.z * NUM_AA + jjC.z];
        o.w = s[iiC.w * NUM_AA + jjC.w];
        out4[v2] = o;
    }
    if (hD) {
        float4 o;
        o.x = s[iiD.x * NUM_AA + jjD.x];
        o.y = s[iiD.y * NUM_AA + jjD.y];
        o.z = s[iiD.z * NUM_AA + jjD.z];
        o.w = s[iiD.w * NUM_AA + jjD.w];
        out4[v3] = o;
    }
}

extern "C" void kernel_launch(void* const* d_in, const int* in_sizes, int n_in,
                              void* d_out, int out_size, void* d_ws, size_t ws_size,
                              hipStream_t stream)
{
    const float* F   = (const float*)d_in[0];
    const float* M   = (const float*)d_in[1];
    const int*   ii  = (const int*)d_in[2];
    const int*   jj  = (const int*)d_in[3];
    float*       out = (float*)d_out;
    float*       tab = (float*)d_ws;   // 400 floats = 1.6 KB scratch

    const int P    = in_sizes[2];
    const int nvec = P >> 2;           // 2,097,152 for P = 8,388,608
    const int tail = nvec << 2;        // first scalar index of tail

    build_table<<<1, 512, 0, stream>>>(F, M, tab, ii, jj, out, tail, P);

    // 2048 blocks x 256 thr x 4 vec4 = 2,097,152 vec4s (exact for this P).
    const int blocks = (nvec + 1023) / 1024;
    gather_pairs<<<blocks, 256, 0, stream>>>(
        tab, (const int4*)ii, (const int4*)jj, (float4*)out, nvec);
}